// Round 4
// baseline (228.636 us; speedup 1.0000x reference)
//
#include <hip/hip_runtime.h>
#include <hip/hip_bf16.h>

// KAN layer fused as one augmented GEMM:
//   out[n][o] = sum_i silu(x[n][i])*scale_base[o][i]
//            + sum_{i,m} basis_m(x[n][i])*scale_sp[o][i]*coef[o][i][m] + bias[o]
// A_aug (8192 x 5376) f16, W_aug (768 x 5376) f16, k = j*768 + i (j=0: silu, j=1..6: basis)
// GEMM: BM=128 BN=96 split-K x2 -> grid 1024 = exactly 4 blocks/CU. atomicAdd epilogue
// into out zeroed by the build kernel (bias folded into k-slice 0).

typedef _Float16 f16;
typedef __attribute__((ext_vector_type(8))) _Float16 f16x8;
typedef __attribute__((ext_vector_type(4))) float f32x4;

#define NTOK 8192
#define DIN 768
#define DOUT 768
#define KAUG 5376   // 7*768
#define BM 128
#define BN 96
#define BK 32
#define KSPLIT 2
#define KSEG (KAUG / KSPLIT)  // 2688
#define KT (KSEG / BK)        // 84

#define A_BLOCKS 3072  // NTOK*(DIN/8)/256
#define W_BLOCKS 288   // DOUT*(DIN/8)/256
#define Z_BLOCKS 1536  // NTOK*DOUT/(256*16)

typedef __attribute__((address_space(1))) void gvoid;
typedef __attribute__((address_space(3))) void lvoid;

// ---------------- Kernel 1: build A_aug, W_aug, and zero out (one launch) ----------------
__global__ __launch_bounds__(256) void build_all(const float* __restrict__ x,
                                                 const float* __restrict__ sb,
                                                 const float* __restrict__ ssp,
                                                 const float* __restrict__ coef,
                                                 f16* __restrict__ Aa,
                                                 f16* __restrict__ Wa,
                                                 float* __restrict__ out) {
  const int b = blockIdx.x;
  if (b < A_BLOCKS) {
    // ---- A part: x -> [silu | 6 basis] f16, 8 elems/thread ----
    const int t = b * 256 + threadIdx.x;  // [0, NTOK*96)
    const int n = t / 96;
    const int i8 = (t - n * 96) * 8;

    const float4* xp = (const float4*)(x + (size_t)n * DIN + i8);
    float4 va = xp[0], vb = xp[1];
    float xv[8] = {va.x, va.y, va.z, va.w, vb.x, vb.y, vb.z, vb.w};

    f16x8 sil;
    f16x8 Bv[6];
#pragma unroll
    for (int e = 0; e < 8; ++e) {
      const float v = xv[e];
      sil[e] = (f16)__fdividef(v, 1.0f + __expf(-v));

      // closed-form uniform cubic B-spline on grid t_g=(g-3)*(2/3)-1
      const float s = (v + 1.0f) * 1.5f + 3.0f;
      const float fi = floorf(s);
      const int i0 = (int)fi;
      const float u = s - fi;
      const float um = 1.0f - u;
      const float u2 = u * u, u3 = u2 * u;
      const float w0 = um * um * um * (1.0f / 6.0f);
      const float w1 = (3.0f * u3 - 6.0f * u2 + 4.0f) * (1.0f / 6.0f);
      const float w2 = (-3.0f * u3 + 3.0f * u2 + 3.0f * u + 1.0f) * (1.0f / 6.0f);
      const float w3 = u3 * (1.0f / 6.0f);
#pragma unroll
      for (int m = 0; m < 6; ++m) {
        const int d = m - i0 + 3;
        float w = (d == 0) ? w0 : (d == 1) ? w1 : (d == 2) ? w2 : (d == 3) ? w3 : 0.0f;
        Bv[m][e] = (f16)w;
      }
    }

    const size_t base = (size_t)n * KAUG + i8;
    *(f16x8*)&Aa[base] = sil;
#pragma unroll
    for (int m = 0; m < 6; ++m) *(f16x8*)&Aa[base + (size_t)(m + 1) * DIN] = Bv[m];
  } else if (b < A_BLOCKS + W_BLOCKS) {
    // ---- W part: [scale_base | scale_sp*coef], 8 elems/thread ----
    const int t = (b - A_BLOCKS) * 256 + threadIdx.x;  // [0, DOUT*96)
    const int o = t / 96;
    const int i8 = (t - o * 96) * 8;
    const size_t idx = (size_t)o * DIN + i8;

    float bb[8], sp[8], cf[48];
    *(float4*)&bb[0] = ((const float4*)(sb + idx))[0];
    *(float4*)&bb[4] = ((const float4*)(sb + idx))[1];
    *(float4*)&sp[0] = ((const float4*)(ssp + idx))[0];
    *(float4*)&sp[4] = ((const float4*)(ssp + idx))[1];
#pragma unroll
    for (int v = 0; v < 12; ++v) *(float4*)&cf[v * 4] = ((const float4*)(coef + idx * 6))[v];

    f16x8 ch0;
    f16x8 chm[6];
#pragma unroll
    for (int e = 0; e < 8; ++e) {
      ch0[e] = (f16)bb[e];
#pragma unroll
      for (int m = 0; m < 6; ++m) chm[m][e] = (f16)(sp[e] * cf[e * 6 + m]);
    }
    const size_t base = (size_t)o * KAUG + i8;
    *(f16x8*)&Wa[base] = ch0;
#pragma unroll
    for (int m = 0; m < 6; ++m) *(f16x8*)&Wa[base + (size_t)(m + 1) * DIN] = chm[m];
  } else {
    // ---- zero out for the atomic split-K epilogue ----
    const int t = (b - A_BLOCKS - W_BLOCKS) * 256 + threadIdx.x;
    float4* o4 = (float4*)out;
    const float4 z = {0.f, 0.f, 0.f, 0.f};
#pragma unroll
    for (int s = 0; s < 4; ++s) o4[(size_t)t * 4 + s] = z;
  }
}

// ---------------- Kernel 2: GEMM C += A_aug * W_aug^T (+bias on slice 0) ----------------
// 128x96 tile, 4 waves (2x2 of 64x48), BK=32, split-K x2, double-buffered LDS,
// single barrier per K-iter (prefetch issued after the barrier). XCD swizzle:
// M-tiles striped across XCDs; both k-slices of a tile land on the same XCD.
__global__ __launch_bounds__(256, 4) void kan_gemm(const f16* __restrict__ A,
                                                   const f16* __restrict__ W,
                                                   const float* __restrict__ bias,
                                                   float* __restrict__ out) {
  __shared__ alignas(16) f16 As[2][BM * BK];  // 2 x 8 KB
  __shared__ alignas(16) f16 Bs[2][BN * BK];  // 2 x 6 KB

  const int bid = blockIdx.x;  // 1024 = 8 XCD * 128 slots
  const int xcd = bid & 7;
  const int slot = bid >> 3;               // 0..127
  const int mb = ((slot & 7) << 3) + xcd;  // 0..63, XCD x owns mb ≡ x (mod 8)
  const int rest = slot >> 3;              // 0..15
  const int nb = rest & 7;                 // 0..7
  const int ks = rest >> 3;                // 0..1
  const int m0 = mb * BM;
  const int n0 = nb * BN;
  const size_t kbase = (size_t)ks * KSEG;

  const int tid = threadIdx.x;
  const int wave = tid >> 6;
  const int lane = tid & 63;
  const int wm = (wave >> 1) * 64;
  const int wn = (wave & 1) * 48;
  const int r = lane & 15;
  const int q = lane >> 4;

  f32x4 acc[4][3] = {};

  // staging chunk c -> row = c>>2, k-quarter = c&3, LDS f16 offset = c*8
  const int c0 = wave * 64 + lane;
  const int rowA0 = c0 >> 2, kq0 = c0 & 3;
  const int c1 = c0 + 256;
  const int rowA1 = c1 >> 2, kq1 = c1 & 3;

  const f16* gA0 = A + (size_t)(m0 + rowA0) * KAUG + kbase + kq0 * 8;
  const f16* gA1 = A + (size_t)(m0 + rowA1) * KAUG + kbase + kq1 * 8;
  const f16* gB0 = W + (size_t)(n0 + rowA0) * KAUG + kbase + kq0 * 8;
  const f16* gB1 = W + (size_t)(n0 + rowA1) * KAUG + kbase + kq1 * 8;  // waves 0,1 only

  const int woff = wave * 512;  // f16 elements; 1 KB per wave

  auto stage = [&](int buf, int kt) {
    const int koff = kt * BK;
    __builtin_amdgcn_global_load_lds((gvoid*)(gA0 + koff), (lvoid*)(&As[buf][woff]), 16, 0, 0);
    __builtin_amdgcn_global_load_lds((gvoid*)(gA1 + koff), (lvoid*)(&As[buf][woff + 2048]), 16, 0, 0);
    __builtin_amdgcn_global_load_lds((gvoid*)(gB0 + koff), (lvoid*)(&Bs[buf][woff]), 16, 0, 0);
    if (wave < 2)  // rows 64..95 of the B tile
      __builtin_amdgcn_global_load_lds((gvoid*)(gB1 + koff), (lvoid*)(&Bs[buf][woff + 2048]), 16, 0, 0);
  };

  stage(0, 0);

  for (int kt = 0; kt < KT; ++kt) {
    const int buf = kt & 1;
    __syncthreads();  // drains prefetch issued ~1 compute-phase ago; syncs LDS reuse
    if (kt + 1 < KT) stage(buf ^ 1, kt + 1);

    f16x8 af[4], bf[3];
#pragma unroll
    for (int mi = 0; mi < 4; ++mi)
      af[mi] = *(const f16x8*)&As[buf][(wm + mi * 16 + r) * BK + q * 8];
#pragma unroll
    for (int ni = 0; ni < 3; ++ni)
      bf[ni] = *(const f16x8*)&Bs[buf][(wn + ni * 16 + r) * BK + q * 8];
#pragma unroll
    for (int mi = 0; mi < 4; ++mi)
#pragma unroll
      for (int ni = 0; ni < 3; ++ni)
        acc[mi][ni] =
            __builtin_amdgcn_mfma_f32_16x16x32_f16(af[mi], bf[ni], acc[mi][ni], 0, 0, 0);
  }

  // epilogue: D mapping col = lane&15, row = q*4 + reg; atomic into zeroed out
#pragma unroll
  for (int ni = 0; ni < 3; ++ni) {
    const int gcol = n0 + wn + ni * 16 + r;
    const float badd = (ks == 0) ? bias[gcol] : 0.0f;
#pragma unroll
    for (int mi = 0; mi < 4; ++mi) {
#pragma unroll
      for (int rg = 0; rg < 4; ++rg) {
        const int grow = m0 + wm + mi * 16 + q * 4 + rg;
        atomicAdd(&out[(size_t)grow * DOUT + gcol], acc[mi][ni][rg] + badd);
      }
    }
  }
}

extern "C" void kernel_launch(void* const* d_in, const int* in_sizes, int n_in,
                              void* d_out, int out_size, void* d_ws, size_t ws_size,
                              hipStream_t stream) {
  const float* x = (const float*)d_in[0];           // (4,2048,768)
  const float* coef = (const float*)d_in[1];        // (768,768,6)
  const float* scale_base = (const float*)d_in[2];  // (768,768)
  const float* scale_sp = (const float*)d_in[3];    // (768,768)
  const float* bias = (const float*)d_in[4];        // (768,)
  float* out = (float*)d_out;                       // (8192,768)

  f16* Aa = (f16*)d_ws;                                     // 8192*5376*2 = 88.1 MB
  f16* Wa = (f16*)((char*)d_ws + (size_t)NTOK * KAUG * 2);  // 768*5376*2  = 8.3 MB

  build_all<<<A_BLOCKS + W_BLOCKS + Z_BLOCKS, 256, 0, stream>>>(x, scale_base, scale_sp,
                                                                coef, Aa, Wa, out);
  kan_gemm<<<8 * 128, 256, 0, stream>>>(Aa, Wa, bias, out);
}